// Round 2
// 358.520 us; speedup vs baseline: 1.0222x; 1.0222x over previous
//
#include <hip/hip_runtime.h>

#define B_  2
#define S_  2048
#define E_  2048
#define H_  16
#define D_  128
#define BS_ (B_*S_)

typedef __bf16 bf16_t;
typedef __bf16 bf16x8 __attribute__((ext_vector_type(8)));
typedef __bf16 bf16x4 __attribute__((ext_vector_type(4)));
typedef float  f32x4  __attribute__((ext_vector_type(4)));
typedef float  f32x16 __attribute__((ext_vector_type(16)));

// combined softmax scale: 1/sqrt(128) * log2(e), folded into Q projection
#define QSCALE 0.1275174131003543f

// ---------------- async global->LDS, 16B per lane per call ----------------
__device__ __forceinline__ void gld16(const bf16_t* g, bf16_t* l) {
    __builtin_amdgcn_global_load_lds(
        (const __attribute__((address_space(1))) void*)g,
        (__attribute__((address_space(3))) void*)l,
        16, 0, 0);
}

// ---------------- fused fp32 -> bf16 convert (x, kv, 4 weights) ----------------
__global__ void cvt_all(const float* __restrict__ s0, const float* __restrict__ s1,
                        const float* __restrict__ s2, const float* __restrict__ s3,
                        const float* __restrict__ s4, const float* __restrict__ s5,
                        bf16_t* d0, bf16_t* d1, bf16_t* d2,
                        bf16_t* d3, bf16_t* d4, bf16_t* d5)
{
    long i = ((long)blockIdx.x * blockDim.x + threadIdx.x) * 4;
    const float* s; bf16_t* d;
    if      (i <  8388608) { s = s0; d = d0; }
    else if (i < 16777216) { s = s1; d = d1; i -=  8388608; }
    else if (i < 20971520) { s = s2; d = d2; i -= 16777216; }
    else if (i < 21233664) { s = s3; d = d3; i -= 20971520; }
    else if (i < 21495808) { s = s4; d = d4; i -= 21233664; }
    else                   { s = s5; d = d5; i -= 21495808; }
    float4 v = *(const float4*)(s + i);
    bf16x4 o;
    o[0] = (bf16_t)v.x; o[1] = (bf16_t)v.y; o[2] = (bf16_t)v.z; o[3] = (bf16_t)v.w;
    *(bf16x4*)(d + i) = o;
}

// ========== GEMM tile core: 128x64 tile, single-buffer gld16 K-loop ==========
template<int EP>
__device__ __forceinline__ void gemm_tile64(
    const bf16_t* __restrict__ A, const bf16_t* __restrict__ W,
    const float* __restrict__ biasA, const float* __restrict__ biasB,
    float* __restrict__ Cf, bf16_t* __restrict__ Cb,
    int N, int K, float scale, int m0, int w_n0, int c_n0,
    bf16_t* As, bf16_t* Bs)
{
    const int tid  = threadIdx.x;
    const int wave = tid >> 6, lane = tid & 63;
    const int wm = wave >> 1, wn = wave & 1;
    const int lrow = lane & 15, quad = lane >> 4;
    const int r8 = lane >> 3, c8 = (lane & 7) << 3;

    f32x4 acc[4][2] = {};

    for (int k0 = 0; k0 < K; k0 += 64) {
        __syncthreads();
#pragma unroll
        for (int j = 0; j < 4; ++j) {
            int base = (wave * 4 + j) * 8;
            gld16(A + (size_t)(m0 + base + r8) * K + k0 + c8, &As[base * 64]);
        }
#pragma unroll
        for (int j = 0; j < 2; ++j) {
            int base = (wave * 2 + j) * 8;
            gld16(W + (size_t)(w_n0 + base + r8) * K + k0 + c8, &Bs[base * 64]);
        }
        __syncthreads();
#pragma unroll
        for (int ks = 0; ks < 2; ++ks) {
            bf16x8 af[4], bfr[2];
#pragma unroll
            for (int mt = 0; mt < 4; ++mt)
                af[mt] = *(const bf16x8*)&As[(wm * 64 + mt * 16 + lrow) * 64 + ks * 32 + quad * 8];
#pragma unroll
            for (int nt = 0; nt < 2; ++nt)
                bfr[nt] = *(const bf16x8*)&Bs[(wn * 32 + nt * 16 + lrow) * 64 + ks * 32 + quad * 8];
#pragma unroll
            for (int mt = 0; mt < 4; ++mt)
#pragma unroll
                for (int nt = 0; nt < 2; ++nt)
                    acc[mt][nt] = __builtin_amdgcn_mfma_f32_16x16x32_bf16(
                        af[mt], bfr[nt], acc[mt][nt], 0, 0, 0);
        }
    }

#pragma unroll
    for (int mt = 0; mt < 4; ++mt) {
#pragma unroll
        for (int nt = 0; nt < 2; ++nt) {
            int nn = wn * 32 + nt * 16 + lrow;
            int col = c_n0 + nn;
            float bvv = (EP == 1 && biasB && col >= 128) ? biasB[col - 128]
                                                         : biasA[col];
#pragma unroll
            for (int r = 0; r < 4; ++r) {
                int row = m0 + wm * 64 + mt * 16 + quad * 4 + r;
                float v = (acc[mt][nt][r] + bvv) * scale;
                if (EP == 0) Cf[(size_t)row * N + col] = v;
                else         Cb[(size_t)row * N + col] = (bf16_t)v;
            }
        }
    }
}

// ---------------- fused Q + K + V projection ----------------
__global__ __launch_bounds__(256) void gemm_qkv(
    const bf16_t* __restrict__ xb, const bf16_t* __restrict__ kvb,
    const bf16_t* __restrict__ Wq, const bf16_t* __restrict__ Wkv,
    const float* __restrict__ bq, const float* __restrict__ bk,
    const float* __restrict__ bv,
    bf16_t* __restrict__ Qb, bf16_t* __restrict__ KVb)
{
    __shared__ __align__(16) bf16_t As[128 * 64];
    __shared__ __align__(16) bf16_t Bs[64 * 64];
    const int m0 = blockIdx.y * 128;
    if (blockIdx.x < 32) {
        int n0 = blockIdx.x * 64;
        gemm_tile64<1>(xb, Wq, bq, nullptr, nullptr, Qb, E_, E_, QSCALE,
                       m0, n0, n0, As, Bs);
    } else {
        int n0 = (blockIdx.x - 32) * 64;
        gemm_tile64<1>(kvb, Wkv, bk, bv, nullptr, KVb, 256, E_, 1.0f,
                       m0, n0, n0, As, Bs);
    }
}

// ---------------- O projection (fp32 out, direct store) ----------------
__global__ __launch_bounds__(256) void gemm_o(
    const bf16_t* __restrict__ A, const bf16_t* __restrict__ W,
    const float* __restrict__ bias, float* __restrict__ Cf)
{
    __shared__ __align__(16) bf16_t As[128 * 64];
    __shared__ __align__(16) bf16_t Bs[64 * 64];
    int n0 = blockIdx.x * 64;
    gemm_tile64<0>(A, W, bias, nullptr, Cf, nullptr, E_, E_, 1.0f,
                   blockIdx.y * 128, n0, n0, As, Bs);
}

// ---------------- flash-style causal MQA attention ----------------
// 4 waves x 32 q-rows (32x32x16 MFMA), swapped QK^T (scores^T: lane owns one
// q-row), in-register softmax; P->A-frag via compiler-fused cvt_pk casts +
// __shfl_xor(,32) cross-half exchange (defined semantics; no P LDS trip).
// Q pre-scaled bf16 [B,S,H,D]; KV interleaved bf16 [B,S,128K|128V]; O bf16.
__global__ __launch_bounds__(256, 2) void mqa_attn(
    const bf16_t* __restrict__ Q, const bf16_t* __restrict__ KV,
    bf16_t* __restrict__ O)
{
    __shared__ __align__(16) bf16_t Kt[64][136];   // [k][d], pad 8
    __shared__ __align__(16) bf16_t Vt[128][72];   // [d][k], pad 8
    __shared__ float rsl[4][32];

    const int bx = blockIdx.x, h = blockIdx.y, b = blockIdx.z;
    const int qb = b ? bx : (15 - bx);             // complementary pairing
    const int tid = threadIdx.x, wave = tid >> 6, lane = tid & 63;
    const int ln = lane & 31, hi = lane >> 5;
    const int q0w = qb * 128 + wave * 32;

    const bf16_t* kvp = KV + (size_t)(b * S_) * 256;

    // Q fragments (B-operand): lane holds Q[q0w+ln][st*16 + hi*8 + j]
    bf16x8 qf[8];
    {
        const bf16_t* qp = Q + ((size_t)(b * S_ + q0w + ln)) * E_ + h * D_ + hi * 8;
#pragma unroll
        for (int st = 0; st < 8; ++st) qf[st] = *(const bf16x8*)(qp + st * 16);
    }

    f32x16 oacc[4] = {};
    float rs = 0.f;

    const int ntiles = 2 * qb + 2;
    bf16x8 kreg[4], vreg[4];

#pragma unroll
    for (int i = 0; i < 4; ++i) {
        int c = tid + 256 * i;
        kreg[i] = *(const bf16x8*)(kvp + (size_t)(c >> 4) * 256 + ((c & 15) << 3));
        vreg[i] = *(const bf16x8*)(kvp + (size_t)(c & 63) * 256 + 128 + ((c >> 6) << 3));
    }

    for (int kt = 0; kt < ntiles; ++kt) {
        const int k_base = kt * 64;
        __syncthreads();
#pragma unroll
        for (int i = 0; i < 4; ++i) {
            int c = tid + 256 * i;
            *(bf16x8*)&Kt[c >> 4][(c & 15) << 3] = kreg[i];
            int n = c & 63, d0 = (c >> 6) << 3;
#pragma unroll
            for (int j = 0; j < 8; ++j) Vt[d0 + j][n] = vreg[i][j];
        }
        __syncthreads();
        if (kt + 1 < ntiles) {
            const int nb = (kt + 1) * 64;
#pragma unroll
            for (int i = 0; i < 4; ++i) {
                int c = tid + 256 * i;
                kreg[i] = *(const bf16x8*)(kvp + (size_t)(nb + (c >> 4)) * 256 + ((c & 15) << 3));
                vreg[i] = *(const bf16x8*)(kvp + (size_t)(nb + (c & 63)) * 256 + 128 + ((c >> 6) << 3));
            }
        }

        if (k_base <= q0w + 31) {      // wave-uniform: skip fully-masked tiles
            // -------- swapped QK^T: sc[ct] = S^T[k= ct*32+rows][q= ln] --------
            f32x16 sc[2] = {f32x16{}, f32x16{}};
#pragma unroll
            for (int st = 0; st < 8; ++st) {
                bf16x8 qv = qf[st];
#pragma unroll
                for (int ct = 0; ct < 2; ++ct) {
                    bf16x8 kf = *(const bf16x8*)&Kt[ct * 32 + ln][st * 16 + hi * 8];
                    sc[ct] = __builtin_amdgcn_mfma_f32_32x32x16_bf16(kf, qv, sc[ct], 0, 0, 0);
                }
            }
            // -------- mask + exp2 softmax (log2-domain scores) --------
            const int qi = q0w + ln;
            const bool diag = (k_base + 63 > q0w);
#pragma unroll
            for (int ct = 0; ct < 2; ++ct) {
#pragma unroll
                for (int r = 0; r < 16; ++r) {
                    float s = sc[ct][r];
                    if (diag) {
                        int kj = k_base + ct * 32 + (r & 3) + 8 * (r >> 2) + 4 * hi;
                        if (kj > qi) s = -1e30f;
                    }
                    float p = exp2f(fminf(s, 110.f));
                    rs += p;
                    sc[ct][r] = p;
                }
            }
            // -------- build PV A-frags in-register: af[ks] = P[q=ln][ks*16+hi*8+j]
            // own-half packs U0..U3 (compiler fuses casts to v_cvt_pk_bf16_f32),
            // other-half packs via __shfl_xor(,32); select by hi.
            bf16x8 af[4];
#pragma unroll
            for (int ks = 0; ks < 4; ++ks) {
                const int c = ks >> 1, b8 = (ks & 1) * 8;
                union { bf16_t h[2]; unsigned u; } pk0, pk1, pk2, pk3;
                pk0.h[0] = (bf16_t)sc[c][b8 + 0]; pk0.h[1] = (bf16_t)sc[c][b8 + 1];
                pk1.h[0] = (bf16_t)sc[c][b8 + 2]; pk1.h[1] = (bf16_t)sc[c][b8 + 3];
                pk2.h[0] = (bf16_t)sc[c][b8 + 4]; pk2.h[1] = (bf16_t)sc[c][b8 + 5];
                pk3.h[0] = (bf16_t)sc[c][b8 + 6]; pk3.h[1] = (bf16_t)sc[c][b8 + 7];
                const unsigned U0 = pk0.u, U1 = pk1.u, U2 = pk2.u, U3 = pk3.u;
                const unsigned V0 = __shfl_xor(U0, 32);
                const unsigned V1 = __shfl_xor(U1, 32);
                const unsigned V2 = __shfl_xor(U2, 32);
                const unsigned V3 = __shfl_xor(U3, 32);
                union { unsigned u[4]; bf16x8 v; } W;
                W.u[0] = hi ? V2 : U0;
                W.u[1] = hi ? V3 : U1;
                W.u[2] = hi ? U2 : V0;
                W.u[3] = hi ? U3 : V1;
                af[ks] = W.v;
            }
            // -------- PV: oacc[t] += P * V, B-frag from transposed Vt --------
#pragma unroll
            for (int ks = 0; ks < 4; ++ks)
#pragma unroll
                for (int t = 0; t < 4; ++t) {
                    bf16x8 vf = *(const bf16x8*)&Vt[t * 32 + ln][ks * 16 + hi * 8];
                    oacc[t] = __builtin_amdgcn_mfma_f32_32x32x16_bf16(af[ks], vf, oacc[t], 0, 0, 0);
                }
        }
    }

    // -------- epilogue: full row sums, deferred normalization --------
    rs += __shfl_xor(rs, 32);
    __syncthreads();
    if (lane < 32) rsl[wave][ln] = 1.0f / rs;
    __syncthreads();
#pragma unroll
    for (int t = 0; t < 4; ++t)
#pragma unroll
        for (int r = 0; r < 16; ++r) {
            int ro = (r & 3) + 8 * (r >> 2) + 4 * hi;
            O[((size_t)(b * S_ + q0w + ro)) * E_ + h * D_ + t * 32 + ln] =
                (bf16_t)(oacc[t][r] * rsl[wave][ro]);
        }
}

// ---------------- launch ----------------
extern "C" void kernel_launch(void* const* d_in, const int* in_sizes, int n_in,
                              void* d_out, int out_size, void* d_ws, size_t ws_size,
                              hipStream_t stream)
{
    const float* x   = (const float*)d_in[0];
    const float* kv  = (const float*)d_in[1];
    const float* Wq  = (const float*)d_in[2];
    const float* bq  = (const float*)d_in[3];
    const float* Wk  = (const float*)d_in[4];
    const float* bk  = (const float*)d_in[5];
    const float* Wv  = (const float*)d_in[6];
    const float* bv  = (const float*)d_in[7];
    const float* Wo  = (const float*)d_in[8];
    const float* bo  = (const float*)d_in[9];
    float* out = (float*)d_out;

    bf16_t* p    = (bf16_t*)d_ws;
    bf16_t* xb   = p;  p += (size_t)BS_ * E_;
    bf16_t* kvb  = p;  p += (size_t)BS_ * E_;
    bf16_t* Wqb  = p;  p += (size_t)E_ * E_;
    bf16_t* Wkvb = p;  p += (size_t)2 * D_ * E_;
    bf16_t* Wob  = p;  p += (size_t)E_ * E_;
    bf16_t* Qb   = p;  p += (size_t)BS_ * E_;
    bf16_t* KVb  = p;  p += (size_t)BS_ * 256;
    bf16_t* Ob   = p;  p += (size_t)BS_ * E_;

    cvt_all<<<dim3(25088), dim3(256), 0, stream>>>(
        x, kv, Wq, Wk, Wv, Wo,
        xb, kvb, Wqb, Wkvb, Wkvb + (size_t)D_ * E_, Wob);

    gemm_qkv<<<dim3(36, BS_ / 128), 256, 0, stream>>>(
        xb, kvb, Wqb, Wkvb, bq, bk, bv, Qb, KVb);

    mqa_attn<<<dim3(S_ / 128, H_, B_), 256, 0, stream>>>(Qb, KVb, Ob);

    gemm_o<<<dim3(E_ / 64, BS_ / 128), 256, 0, stream>>>(Ob, Wob, bo, out);
}